// Round 4
// baseline (373.570 us; speedup 1.0000x reference)
//
#include <hip/hip_runtime.h>

#define RADIUS 3
#define C_CH 128
#define N_FR 16
#define H0 120
#define W0 160
#define HW0 (H0*W0)
#define H1 30
#define W1 40
#define EXT 10
#define NCELL 100
#define M_PT 1536
#define FM1SZ (N_FR*H1*W1*C_CH)     // fm1T [N][H1][W1][C] floats
#define GT_SZ (M_PT*9*C_CH)         // gmapT [M][9][C] floats
#define SCSTR 12                    // sC dword stride per cell

// 4x4 average pool, output channel-last: fm1T[n][y][x][c]
__global__ __launch_bounds__(128) void pool_kernel(const float* __restrict__ fm0,
                                                   float* __restrict__ fm1T) {
    int b = blockIdx.x;                 // (n*H1 + y)*W1 + x
    int c = threadIdx.x;
    int x = b % W1;
    int y = (b / W1) % H1;
    int n = b / (W1 * H1);
    const float* src = fm0 + (((size_t)n * C_CH + c) * H0 + y * 4) * W0 + x * 4;
    float s = 0.f;
#pragma unroll
    for (int r = 0; r < 4; ++r) {
        float4 v = *reinterpret_cast<const float4*>(src + r * W0);
        s += v.x + v.y + v.z + v.w;
    }
    fm1T[(size_t)b * C_CH + c] = s * (1.f / 16.f);
}

// gmap [M][C][9] -> gmapT [M][9][C]
__global__ __launch_bounds__(128) void gtrans_kernel(const float* __restrict__ g,
                                                     float* __restrict__ gT) {
    int m = blockIdx.x;
    const float* src = g + (size_t)m * (C_CH * 9);
    float* dst = gT + (size_t)m * (C_CH * 9);
    for (int o = threadIdx.x; o < C_CH * 9; o += 128) {
        int c = o & (C_CH - 1);
        int pq = o >> 7;
        dst[o] = src[c * 9 + pq];
    }
}

__global__ void zero_kernel(int* cnt) {
    if (threadIdx.x < 32) cnt[threadIdx.x] = 0;
}

__global__ void hist_kernel(const int* __restrict__ jj, int* __restrict__ cnt, int E) {
    __shared__ int h[N_FR];
    int tid = threadIdx.x;
    if (tid < N_FR) h[tid] = 0;
    __syncthreads();
    int e = blockIdx.x * blockDim.x + tid;
    if (e < E) atomicAdd(&h[jj[e]], 1);
    __syncthreads();
    if (tid < N_FR && h[tid] > 0) atomicAdd(&cnt[tid], h[tid]);
}

__global__ void scan_kernel(const int* __restrict__ cnt, int* __restrict__ off) {
    if (threadIdx.x == 0) {
        int s = 0;
        for (int f = 0; f < N_FR; ++f) { off[f] = s; s += cnt[f]; }
    }
}

__global__ void scatter_kernel(const int* __restrict__ jj, int* __restrict__ off,
                               int* __restrict__ perm, int E) {
    __shared__ int h[N_FR];
    __shared__ int base[N_FR];
    int tid = threadIdx.x;
    if (tid < N_FR) h[tid] = 0;
    __syncthreads();
    int e = blockIdx.x * blockDim.x + tid;
    int f = 0, rank = 0;
    if (e < E) {
        f = jj[e];
        rank = atomicAdd(&h[f], 1);
    }
    __syncthreads();
    if (tid < N_FR && h[tid] > 0) base[tid] = atomicAdd(&off[tid], h[tid]);
    __syncthreads();
    if (e < E) perm[base[f] + rank] = e;
}

// One block (128 thr) per edge; thread = union-window cell, both levels fused.
__global__ __launch_bounds__(128) void corr_kernel(
        const float* __restrict__ fmap,   // [N,C,H0,W0]
        const float* __restrict__ fm1T,   // [N,H1,W1,C]
        const float* __restrict__ gmap,   // [M,C,3,3]
        const float* __restrict__ gmapT,  // [M,9,C] or null
        const float* __restrict__ coords, // [E,3,3,2]
        const int* __restrict__ ii,
        const int* __restrict__ jj,
        const int* __restrict__ perm,     // frame-sorted order or null
        float* __restrict__ out) {        // [E,7,7,3,3,2]
    __shared__ float sC[2 * NCELL * SCSTR];   // [lvl][cell][pq]

    int e = perm ? perm[blockIdx.x] : (int)blockIdx.x;
    int tid = threadIdx.x;

    int iie = __builtin_amdgcn_readfirstlane(ii[e]);
    int jje = __builtin_amdgcn_readfirstlane(jj[e]);
    const float* cb = coords + (size_t)e * 18;

    float cx = cb[0], cy = cb[1];
    int bx0 = (int)floorf(cx) - RADIUS;
    int by0 = (int)floorf(cy) - RADIUS;
    int bx1 = (int)floorf(cx * 0.25f) - RADIUS;
    int by1 = (int)floorf(cy * 0.25f) - RADIUS;

    // per-thread cell (lanes >= NCELL redundantly compute cell 99; no divergence)
    int cell = min(tid, NCELL - 1);
    int iy = cell / EXT, ix = cell - iy * EXT;
    int gy0 = min(max(by0 + iy, 0), H0 - 1);
    int gx0 = min(max(bx0 + ix, 0), W0 - 1);
    int gy1 = min(max(by1 + iy, 0), H1 - 1);
    int gx1 = min(max(bx1 + ix, 0), W1 - 1);

    const float* fp0 = fmap + (size_t)jje * C_CH * HW0 + gy0 * W0 + gx0;
    const float* fp1 = fm1T + (((size_t)jje * H1 + gy1) * W1 + gx1) * C_CH;

    float acc0[9], acc1[9];
#pragma unroll
    for (int pq = 0; pq < 9; ++pq) { acc0[pq] = 0.f; acc1[pq] = 0.f; }

    if (gmapT) {
        const float* gp = gmapT + (size_t)iie * (9 * C_CH);
#pragma unroll 4
        for (int c = 0; c < C_CH; c += 4) {
            float f0 = fp0[(size_t)(c + 0) * HW0];
            float f1 = fp0[(size_t)(c + 1) * HW0];
            float f2 = fp0[(size_t)(c + 2) * HW0];
            float f3 = fp0[(size_t)(c + 3) * HW0];
            float4 fv = *reinterpret_cast<const float4*>(fp1 + c);
#pragma unroll
            for (int pq = 0; pq < 9; ++pq) {
                float4 g4 = *reinterpret_cast<const float4*>(gp + pq * C_CH + c);
                acc0[pq] += f0 * g4.x + f1 * g4.y + f2 * g4.z + f3 * g4.w;
                acc1[pq] += fv.x * g4.x + fv.y * g4.y + fv.z * g4.z + fv.w * g4.w;
            }
        }
    } else {
        const float* gp = gmap + (size_t)iie * (C_CH * 9);
#pragma unroll 2
        for (int c = 0; c < C_CH; c += 4) {
            float f0 = fp0[(size_t)(c + 0) * HW0];
            float f1 = fp0[(size_t)(c + 1) * HW0];
            float f2 = fp0[(size_t)(c + 2) * HW0];
            float f3 = fp0[(size_t)(c + 3) * HW0];
            float4 fv = *reinterpret_cast<const float4*>(fp1 + c);
#pragma unroll
            for (int pq = 0; pq < 9; ++pq) {
                float g0 = gp[(c + 0) * 9 + pq];
                float g1 = gp[(c + 1) * 9 + pq];
                float g2 = gp[(c + 2) * 9 + pq];
                float g3 = gp[(c + 3) * 9 + pq];
                acc0[pq] += f0 * g0 + f1 * g1 + f2 * g2 + f3 * g3;
                acc1[pq] += fv.x * g0 + fv.y * g1 + fv.z * g2 + fv.w * g3;
            }
        }
    }

    if (tid < NCELL) {
        float* s0 = &sC[cell * SCSTR];
        float* s1 = &sC[NCELL * SCSTR + cell * SCSTR];
        *reinterpret_cast<float4*>(s0)     = float4{acc0[0], acc0[1], acc0[2], acc0[3]};
        *reinterpret_cast<float4*>(s0 + 4) = float4{acc0[4], acc0[5], acc0[6], acc0[7]};
        s0[8] = acc0[8];
        *reinterpret_cast<float4*>(s1)     = float4{acc1[0], acc1[1], acc1[2], acc1[3]};
        *reinterpret_cast<float4*>(s1 + 4) = float4{acc1[4], acc1[5], acc1[6], acc1[7]};
        s1[8] = acc1[8];
    }
    __syncthreads();

    for (int o = tid; o < 882; o += 128) {
        int lvl = o & 1;
        int r = o >> 1;           // (a*7+b)*9 + pq
        int pq = r % 9;
        int ab = r / 9;
        int a = ab / 7, b = ab - a * 7;
        float s = lvl ? 0.25f : 1.f;
        float x = cb[pq * 2 + 0] * s;
        float y = cb[pq * 2 + 1] * s;
        float x0f = floorf(x), y0f = floorf(y);
        float fx = x - x0f, fy = y - y0f;
        int offx = (int)x0f - RADIUS - (lvl ? bx1 : bx0);
        int offy = (int)y0f - RADIUS - (lvl ? by1 : by0);
        int cell2 = (offy + a) * EXT + (offx + b);
        int base = lvl * (NCELL * SCSTR) + cell2 * SCSTR + pq;
        float c00 = sC[base];
        float c01 = sC[base + SCSTR];
        float c10 = sC[base + EXT * SCSTR];
        float c11 = sC[base + EXT * SCSTR + SCSTR];
        float v = (1.f - fy) * (1.f - fx) * c00 + (1.f - fy) * fx * c01
                + fy * (1.f - fx) * c10 + fy * fx * c11;
        out[(size_t)e * 882 + (size_t)r * 2 + lvl] = v;
    }
}

extern "C" void kernel_launch(void* const* d_in, const int* in_sizes, int n_in,
                              void* d_out, int out_size, void* d_ws, size_t ws_size,
                              hipStream_t stream) {
    const float* fmap   = (const float*)d_in[0];
    const float* gmap   = (const float*)d_in[1];
    const float* coords = (const float*)d_in[2];
    const int* ii       = (const int*)d_in[3];
    const int* jj       = (const int*)d_in[4];
    float* out = (float*)d_out;

    int E = in_sizes[3];

    float* fm1T = (float*)d_ws;                       // FM1SZ floats (proven to fit)
    int* cnt  = (int*)d_ws + FM1SZ;                   // [16]
    int* off  = cnt + N_FR;                           // [16]
    int* perm = off + N_FR;                           // [E]
    float* gmapT = (float*)(perm + E);                // GT_SZ floats

    size_t need_perm = ((size_t)FM1SZ + 32 + E) * 4;
    size_t need_gT   = need_perm + (size_t)GT_SZ * 4;

    pool_kernel<<<N_FR * H1 * W1, 128, 0, stream>>>(fmap, fm1T);

    const float* gT_arg = nullptr;
    if (ws_size >= need_gT) {
        gtrans_kernel<<<M_PT, 128, 0, stream>>>(gmap, gmapT);
        gT_arg = gmapT;
    }

    const int* perm_arg = nullptr;
    if (ws_size >= need_perm) {
        int nb = (E + 255) / 256;
        zero_kernel<<<1, 64, 0, stream>>>(cnt);
        hist_kernel<<<nb, 256, 0, stream>>>(jj, cnt, E);
        scan_kernel<<<1, 64, 0, stream>>>(cnt, off);
        scatter_kernel<<<nb, 256, 0, stream>>>(jj, off, perm, E);
        perm_arg = perm;
    }

    corr_kernel<<<E, 128, 0, stream>>>(fmap, fm1T, gmap, gT_arg, coords, ii, jj,
                                       perm_arg, out);
}

// Round 5
// 224.234 us; speedup vs baseline: 1.6660x; 1.6660x over previous
//
#include <hip/hip_runtime.h>

#define RADIUS 3
#define C_CH 128
#define N_FR 16
#define H0 120
#define W0 160
#define HW0 (H0*W0)
#define H1 30
#define W1 40
#define EXT 10
#define NCELL 100
#define M_PT 1536
#define FM1SZ (N_FR*H1*W1*C_CH)     // fm1T [N][H1][W1][C] floats (also planar tmp size)
#define GT_SZ (M_PT*9*C_CH)         // gmapT [M][9][C] floats
#define SCSTR 12                    // sC dword stride per cell
#define NBKT 256                    // sort buckets: frame*16 + y-band

// ---- planar 4x4 average pool (coalesced): fm0 [N,C,120,160] -> tmp [N,C,30,40] ----
__global__ __launch_bounds__(256) void pool_kernel(const float* __restrict__ fm0,
                                                   float* __restrict__ tmp) {
    int idx = blockIdx.x * blockDim.x + threadIdx.x;
    int total = N_FR * C_CH * H1 * W1;
    if (idx >= total) return;
    int x = idx % W1;
    int y = (idx / W1) % H1;
    int nc = idx / (W1 * H1);
    const float* src = fm0 + ((size_t)nc * H0 + y * 4) * W0 + x * 4;
    float s = 0.f;
#pragma unroll
    for (int dy = 0; dy < 4; ++dy) {
        float4 v = *reinterpret_cast<const float4*>(src + dy * W0);
        s += v.x + v.y + v.z + v.w;
    }
    tmp[idx] = s * (1.f / 16.f);
}

// ---- tmp [N,C,30,40] -> fm1T [N,30,40,C], LDS transpose, both sides coalesced ----
__global__ __launch_bounds__(256) void fm1_transpose(const float* __restrict__ src,
                                                     float* __restrict__ dst) {
    __shared__ float s[C_CH * 41];
    int b = blockIdx.x;            // n*H1 + y
    int y = b % H1;
    int n = b / H1;
    for (int t = threadIdx.x; t < C_CH * W1; t += 256) {
        int c = t / W1, x = t - c * W1;
        s[c * 41 + x] = src[((size_t)(n * C_CH + c) * H1 + y) * W1 + x];
    }
    __syncthreads();
    float* dp = dst + (size_t)b * W1 * C_CH;
    for (int t = threadIdx.x; t < W1 * C_CH; t += 256) {
        int x = t >> 7, c = t & 127;
        dp[(size_t)x * C_CH + c] = s[c * 41 + x];
    }
}

// ---- gmap [M][C][9] -> gmapT [M][9][C] ----
__global__ __launch_bounds__(128) void gtrans_kernel(const float* __restrict__ g,
                                                     float* __restrict__ gT) {
    int m = blockIdx.x;
    const float* src = g + (size_t)m * (C_CH * 9);
    float* dst = gT + (size_t)m * (C_CH * 9);
    for (int o = threadIdx.x; o < C_CH * 9; o += 128) {
        int c = o & (C_CH - 1);
        int pq = o >> 7;
        dst[o] = src[c * 9 + pq];
    }
}

// ---- (frame, y-band) bucket sort ----
__device__ __forceinline__ int sort_key(const int* jj, const float* coords, int e) {
    float cy = coords[(size_t)e * 18 + 1];
    int by0 = (int)floorf(cy) - RADIUS;
    int band = min(max(by0 >> 3, 0), 15);
    return jj[e] * 16 + band;
}

__global__ void zero_kernel(int* cnt) {
    int t = blockIdx.x * blockDim.x + threadIdx.x;
    if (t < 2 * NBKT) cnt[t] = 0;
}

__global__ void hist_kernel(const int* __restrict__ jj, const float* __restrict__ coords,
                            int* __restrict__ cnt, int E) {
    __shared__ int h[NBKT];
    int tid = threadIdx.x;
    h[tid] = 0;
    __syncthreads();
    int e = blockIdx.x * blockDim.x + tid;
    if (e < E) atomicAdd(&h[sort_key(jj, coords, e)], 1);
    __syncthreads();
    if (h[tid] > 0) atomicAdd(&cnt[tid], h[tid]);
}

__global__ void scan_kernel(const int* __restrict__ cnt, int* __restrict__ off) {
    if (threadIdx.x == 0) {
        int s = 0;
        for (int f = 0; f < NBKT; ++f) { off[f] = s; s += cnt[f]; }
    }
}

__global__ void scatter_kernel(const int* __restrict__ jj, const float* __restrict__ coords,
                               int* __restrict__ off, int* __restrict__ perm, int E) {
    __shared__ int h[NBKT];
    __shared__ int base[NBKT];
    int tid = threadIdx.x;
    h[tid] = 0;
    __syncthreads();
    int e = blockIdx.x * blockDim.x + tid;
    int k = 0, rank = 0;
    if (e < E) {
        k = sort_key(jj, coords, e);
        rank = atomicAdd(&h[k], 1);
    }
    __syncthreads();
    if (h[tid] > 0) base[tid] = atomicAdd(&off[tid], h[tid]);
    __syncthreads();
    if (e < E) perm[base[k] + rank] = e;
}

// ---- One block (128 thr) per edge; thread = union-window cell, both levels fused ----
__global__ __launch_bounds__(128) void corr_kernel(
        const float* __restrict__ fmap,   // [N,C,H0,W0]
        const float* __restrict__ fm1T,   // [N,H1,W1,C]
        const float* __restrict__ gmap,   // [M,C,3,3]
        const float* __restrict__ gmapT,  // [M,9,C] or null
        const float* __restrict__ coords, // [E,3,3,2]
        const int* __restrict__ ii,
        const int* __restrict__ jj,
        const int* __restrict__ perm,     // sorted order or null
        float* __restrict__ out) {        // [E,7,7,3,3,2]
    __shared__ float sC[2 * NCELL * SCSTR];   // [lvl][cell][pq]

    int e = perm ? perm[blockIdx.x] : (int)blockIdx.x;
    int tid = threadIdx.x;

    int iie = __builtin_amdgcn_readfirstlane(ii[e]);
    int jje = __builtin_amdgcn_readfirstlane(jj[e]);
    const float* cb = coords + (size_t)e * 18;

    float cx = cb[0], cy = cb[1];
    int bx0 = (int)floorf(cx) - RADIUS;
    int by0 = (int)floorf(cy) - RADIUS;
    int bx1 = (int)floorf(cx * 0.25f) - RADIUS;
    int by1 = (int)floorf(cy * 0.25f) - RADIUS;

    int cell = min(tid, NCELL - 1);
    int iy = cell / EXT, ix = cell - iy * EXT;
    int gy0 = min(max(by0 + iy, 0), H0 - 1);
    int gx0 = min(max(bx0 + ix, 0), W0 - 1);
    int gy1 = min(max(by1 + iy, 0), H1 - 1);
    int gx1 = min(max(bx1 + ix, 0), W1 - 1);

    const float* fp0 = fmap + (size_t)jje * C_CH * HW0 + gy0 * W0 + gx0;
    const float* fp1 = fm1T + (((size_t)jje * H1 + gy1) * W1 + gx1) * C_CH;

    float acc0[9], acc1[9];
#pragma unroll
    for (int pq = 0; pq < 9; ++pq) { acc0[pq] = 0.f; acc1[pq] = 0.f; }

    if (gmapT) {
        const float* gp = gmapT + (size_t)iie * (9 * C_CH);
#pragma unroll 4
        for (int c = 0; c < C_CH; c += 4) {
            float f0 = fp0[(size_t)(c + 0) * HW0];
            float f1 = fp0[(size_t)(c + 1) * HW0];
            float f2 = fp0[(size_t)(c + 2) * HW0];
            float f3 = fp0[(size_t)(c + 3) * HW0];
            float4 fv = *reinterpret_cast<const float4*>(fp1 + c);
#pragma unroll
            for (int pq = 0; pq < 9; ++pq) {
                float4 g4 = *reinterpret_cast<const float4*>(gp + pq * C_CH + c);
                acc0[pq] += f0 * g4.x + f1 * g4.y + f2 * g4.z + f3 * g4.w;
                acc1[pq] += fv.x * g4.x + fv.y * g4.y + fv.z * g4.z + fv.w * g4.w;
            }
        }
    } else {
        const float* gp = gmap + (size_t)iie * (C_CH * 9);
#pragma unroll 2
        for (int c = 0; c < C_CH; c += 4) {
            float f0 = fp0[(size_t)(c + 0) * HW0];
            float f1 = fp0[(size_t)(c + 1) * HW0];
            float f2 = fp0[(size_t)(c + 2) * HW0];
            float f3 = fp0[(size_t)(c + 3) * HW0];
            float4 fv = *reinterpret_cast<const float4*>(fp1 + c);
#pragma unroll
            for (int pq = 0; pq < 9; ++pq) {
                float g0 = gp[(c + 0) * 9 + pq];
                float g1 = gp[(c + 1) * 9 + pq];
                float g2 = gp[(c + 2) * 9 + pq];
                float g3 = gp[(c + 3) * 9 + pq];
                acc0[pq] += f0 * g0 + f1 * g1 + f2 * g2 + f3 * g3;
                acc1[pq] += fv.x * g0 + fv.y * g1 + fv.z * g2 + fv.w * g3;
            }
        }
    }

    if (tid < NCELL) {
        float* s0 = &sC[cell * SCSTR];
        float* s1 = &sC[NCELL * SCSTR + cell * SCSTR];
        *reinterpret_cast<float4*>(s0)     = float4{acc0[0], acc0[1], acc0[2], acc0[3]};
        *reinterpret_cast<float4*>(s0 + 4) = float4{acc0[4], acc0[5], acc0[6], acc0[7]};
        s0[8] = acc0[8];
        *reinterpret_cast<float4*>(s1)     = float4{acc1[0], acc1[1], acc1[2], acc1[3]};
        *reinterpret_cast<float4*>(s1 + 4) = float4{acc1[4], acc1[5], acc1[6], acc1[7]};
        s1[8] = acc1[8];
    }
    __syncthreads();

    for (int o = tid; o < 882; o += 128) {
        int lvl = o & 1;
        int r = o >> 1;           // (a*7+b)*9 + pq
        int pq = r % 9;
        int ab = r / 9;
        int a = ab / 7, b = ab - a * 7;
        float s = lvl ? 0.25f : 1.f;
        float x = cb[pq * 2 + 0] * s;
        float y = cb[pq * 2 + 1] * s;
        float x0f = floorf(x), y0f = floorf(y);
        float fx = x - x0f, fy = y - y0f;
        int offx = (int)x0f - RADIUS - (lvl ? bx1 : bx0);
        int offy = (int)y0f - RADIUS - (lvl ? by1 : by0);
        int cell2 = (offy + a) * EXT + (offx + b);
        int base = lvl * (NCELL * SCSTR) + cell2 * SCSTR + pq;
        float c00 = sC[base];
        float c01 = sC[base + SCSTR];
        float c10 = sC[base + EXT * SCSTR];
        float c11 = sC[base + EXT * SCSTR + SCSTR];
        float v = (1.f - fy) * (1.f - fx) * c00 + (1.f - fy) * fx * c01
                + fy * (1.f - fx) * c10 + fy * fx * c11;
        out[(size_t)e * 882 + (size_t)r * 2 + lvl] = v;
    }
}

extern "C" void kernel_launch(void* const* d_in, const int* in_sizes, int n_in,
                              void* d_out, int out_size, void* d_ws, size_t ws_size,
                              hipStream_t stream) {
    const float* fmap   = (const float*)d_in[0];
    const float* gmap   = (const float*)d_in[1];
    const float* coords = (const float*)d_in[2];
    const int* ii       = (const int*)d_in[3];
    const int* jj       = (const int*)d_in[4];
    float* out = (float*)d_out;

    int E = in_sizes[3];

    float* fm1T = (float*)d_ws;                       // FM1SZ floats
    int* cnt  = (int*)d_ws + FM1SZ;                   // [256]
    int* off  = cnt + NBKT;                           // [256]
    int* perm = off + NBKT;                           // [E]
    float* gmapT = (float*)(perm + E);                // GT_SZ floats

    size_t need_perm = ((size_t)FM1SZ + 2 * NBKT + E) * 4;
    size_t need_gT   = need_perm + (size_t)GT_SZ * 4;

    // planar pool into d_out scratch (fully overwritten by corr afterwards),
    // then coalesced LDS transpose into fm1T
    float* tmp = out;   // out_size = 882*E floats >= FM1SZ
    int total1 = N_FR * C_CH * H1 * W1;
    pool_kernel<<<(total1 + 255) / 256, 256, 0, stream>>>(fmap, tmp);
    fm1_transpose<<<N_FR * H1, 256, 0, stream>>>(tmp, fm1T);

    const float* gT_arg = nullptr;
    if (ws_size >= need_gT) {
        gtrans_kernel<<<M_PT, 128, 0, stream>>>(gmap, gmapT);
        gT_arg = gmapT;
    }

    const int* perm_arg = nullptr;
    if (ws_size >= need_perm) {
        int nb = (E + NBKT - 1) / NBKT;
        zero_kernel<<<(2 * NBKT + 255) / 256, 256, 0, stream>>>(cnt);
        hist_kernel<<<nb, NBKT, 0, stream>>>(jj, coords, cnt, E);
        scan_kernel<<<1, 64, 0, stream>>>(cnt, off);
        scatter_kernel<<<nb, NBKT, 0, stream>>>(jj, coords, off, perm, E);
        perm_arg = perm;
    }

    corr_kernel<<<E, 128, 0, stream>>>(fmap, fm1T, gmap, gT_arg, coords, ii, jj,
                                       perm_arg, out);
}